// Round 4
// baseline (24.584 us; speedup 1.0000x reference)
//
#include <hip/hip_runtime.h>
#include <hip/hip_bf16.h>

// Tree-MLP via bf16 MFMA (16x16x32), fp32 accumulate. v4: ILP/MLP-focused.
//  - swapped product D[n][m] = W^T X^T per node; D layout (col=sample, row=4g+r)
//    feeds the next layer's B fragment under k-map k(g,j)=4g+j | 16+4g+(j-4).
//  - TPI=2: two 16-sample tiles interleaved per iteration -> 2 independent
//    dependency chains at every MFMA/cvt step, 2x outstanding loads.
//  - f32 biases in regs (no per-tile unpack), nt stores only.

typedef __attribute__((ext_vector_type(8))) short bf16x8;   // 8 bf16 = 4 VGPRs
typedef __attribute__((ext_vector_type(4))) float f32x4;    // 4 fp32

__device__ __forceinline__ short bfr(float f) {
  return (short)__builtin_bit_cast(unsigned short, __float2bfloat16(f));
}
__device__ __forceinline__ float relu_(float a) { return fmaxf(a, 0.0f); }

__global__ __launch_bounds__(256, 3) void tree_mlp_mfma4(
    const float* __restrict__ x,
    const float* __restrict__ W1, const float* __restrict__ b1,
    const float* __restrict__ W2, const float* __restrict__ b2,
    const float* __restrict__ W3, const float* __restrict__ b3,
    const float* __restrict__ W4, const float* __restrict__ b4,
    float* __restrict__ out, int ntiles) {
  const int lane = threadIdx.x & 63;
  const int n = lane & 15;   // output feature row / sample col
  const int g = lane >> 4;   // lane group 0..3

  const int wpb = blockDim.x >> 6;
  const int gw = blockIdx.x * wpb + (threadIdx.x >> 6);
  const int nw = gridDim.x * wpb;

  // ---------------- weight fragments (loop-invariant) ----------------
  bf16x8 w1f[8];
#pragma unroll
  for (int i = 0; i < 8; ++i) {
    bf16x8 f;
#pragma unroll
    for (int j = 0; j < 8; ++j) f[j] = (short)0;
#pragma unroll
    for (int j = 0; j < 4; ++j) {
      int k = 4 * g + j;
      float v = 0.0f;
      if (k == 2 * i)     v = W1[i * 32 + n];
      if (k == 2 * i + 1) v = W1[i * 32 + 16 + n];
      f[j] = bfr(v);
    }
    if (g == 0) f[4] = bfr(b1[i * 16 + n]);   // bias in k==16 slot
    w1f[i] = f;
  }
  bf16x8 w2f[4]; f32x4 c2[4];
#pragma unroll
  for (int i = 0; i < 4; ++i) {
    bf16x8 f;
#pragma unroll
    for (int j = 0; j < 4; ++j) f[j]     = bfr(W2[i * 512 + (4 * g + j) * 16 + n]);
#pragma unroll
    for (int j = 0; j < 4; ++j) f[4 + j] = bfr(W2[i * 512 + (16 + 4 * g + j) * 16 + n]);
    w2f[i] = f;
#pragma unroll
    for (int r = 0; r < 4; ++r) c2[i][r] = b2[i * 16 + 4 * g + r];
  }
  bf16x8 w3f[2]; f32x4 c3[2];
#pragma unroll
  for (int i = 0; i < 2; ++i) {
    bf16x8 f;
#pragma unroll
    for (int j = 0; j < 4; ++j) f[j]     = bfr(W3[i * 512 + (4 * g + j) * 16 + n]);
#pragma unroll
    for (int j = 0; j < 4; ++j) f[4 + j] = bfr(W3[i * 512 + (16 + 4 * g + j) * 16 + n]);
    w3f[i] = f;
#pragma unroll
    for (int r = 0; r < 4; ++r) c3[i][r] = b3[i * 16 + 4 * g + r];
  }
  bf16x8 w4f; f32x4 c4;
  {
    bf16x8 f;
#pragma unroll
    for (int j = 0; j < 4; ++j) f[j]     = bfr(W4[(4 * g + j) * 16 + n]);
#pragma unroll
    for (int j = 0; j < 4; ++j) f[4 + j] = bfr(W4[(16 + 4 * g + j) * 16 + n]);
    w4f = f;
#pragma unroll
    for (int r = 0; r < 4; ++r) c4[r] = b4[4 * g + r];
  }

  const short bias_slot = (g == 0) ? bfr(1.0f) : (short)0;
  const f32x4* __restrict__ xf = reinterpret_cast<const f32x4*>(x);
  f32x4* __restrict__ of = reinterpret_cast<f32x4*>(out);

  const int nsuper = ntiles >> 1;   // 2 tiles per supertile
  int s = gw;
  if (s >= nsuper) return;

  // lane (n,g) owns sample row 16t+n, features [4g,4g+3] -> one 16B load
  f32x4 xa0 = xf[(size_t)((2 * s)     * 16 + n) * 4 + g];
  f32x4 xa1 = xf[(size_t)((2 * s + 1) * 16 + n) * 4 + g];

  for (; s < nsuper; s += nw) {
    const int sn = s + nw;
    f32x4 xn0 = xa0, xn1 = xa1;
    if (sn < nsuper) {   // prefetch next supertile's 2 tiles at loop top
      xn0 = xf[(size_t)((2 * sn)     * 16 + n) * 4 + g];
      xn1 = xf[(size_t)((2 * sn + 1) * 16 + n) * 4 + g];
    }

    // level-1 B fragments: x^T with constant-1 bias feature at k==16
    bf16x8 xb[2];
#pragma unroll
    for (int u = 0; u < 2; ++u) {
      const f32x4 xv = (u == 0) ? xa0 : xa1;
      bf16x8 f;
      f[0] = bfr(xv[0]); f[1] = bfr(xv[1]); f[2] = bfr(xv[2]); f[3] = bfr(xv[3]);
      f[4] = bias_slot; f[5] = 0; f[6] = 0; f[7] = 0;
      xb[u] = f;
    }

    const f32x4 zero = {0.f, 0.f, 0.f, 0.f};

    // L1 pair -> L2, both tiles interleaved (2 independent chains)
    f32x4 a2[2][4];
#pragma unroll
    for (int i = 0; i < 4; ++i) {
#pragma unroll
      for (int u = 0; u < 2; ++u) {
        f32x4 aL = __builtin_amdgcn_mfma_f32_16x16x32_bf16(w1f[2 * i],     xb[u], zero, 0, 0, 0);
        f32x4 aR = __builtin_amdgcn_mfma_f32_16x16x32_bf16(w1f[2 * i + 1], xb[u], zero, 0, 0, 0);
        bf16x8 hb;
#pragma unroll
        for (int r = 0; r < 4; ++r) {
          hb[r]     = bfr(relu_(aL[r]));
          hb[4 + r] = bfr(relu_(aR[r]));
        }
        a2[u][i] = __builtin_amdgcn_mfma_f32_16x16x32_bf16(w2f[i], hb, c2[i], 0, 0, 0);
      }
    }

    f32x4 a3[2][2];
#pragma unroll
    for (int i = 0; i < 2; ++i) {
#pragma unroll
      for (int u = 0; u < 2; ++u) {
        bf16x8 hb;
#pragma unroll
        for (int r = 0; r < 4; ++r) {
          hb[r]     = bfr(relu_(a2[u][2 * i][r]));
          hb[4 + r] = bfr(relu_(a2[u][2 * i + 1][r]));
        }
        a3[u][i] = __builtin_amdgcn_mfma_f32_16x16x32_bf16(w3f[i], hb, c3[i], 0, 0, 0);
      }
    }

    f32x4 a4[2];
#pragma unroll
    for (int u = 0; u < 2; ++u) {
      bf16x8 hb;
#pragma unroll
      for (int r = 0; r < 4; ++r) {
        hb[r]     = bfr(relu_(a3[u][0][r]));
        hb[4 + r] = bfr(relu_(a3[u][1][r]));
      }
      a4[u] = __builtin_amdgcn_mfma_f32_16x16x32_bf16(w4f, hb, c4, 0, 0, 0);
    }

#pragma unroll
    for (int u = 0; u < 2; ++u) {
      f32x4 o;
#pragma unroll
      for (int r = 0; r < 4; ++r) o[r] = relu_(a4[u][r]);
      __builtin_nontemporal_store(o, &of[(size_t)((2 * s + u) * 16 + n) * 4 + g]);
    }

    xa0 = xn0;
    xa1 = xn1;
  }
}

extern "C" void kernel_launch(void* const* d_in, const int* in_sizes, int n_in,
                              void* d_out, int out_size, void* d_ws, size_t ws_size,
                              hipStream_t stream) {
  const float* x  = (const float*)d_in[0];
  const float* W1 = (const float*)d_in[1];
  const float* b1 = (const float*)d_in[2];
  const float* W2 = (const float*)d_in[3];
  const float* b2 = (const float*)d_in[4];
  const float* W3 = (const float*)d_in[5];
  const float* b3 = (const float*)d_in[6];
  const float* W4 = (const float*)d_in[7];
  const float* b4 = (const float*)d_in[8];
  float* out = (float*)d_out;

  const int ntiles = in_sizes[0] / 256;   // 16 samples x 16 features per tile
  const int block = 256;                  // 4 waves/block
  const int grid = 768;                   // 3 blocks/CU resident (256,3 bound)
  tree_mlp_mfma4<<<grid, block, 0, stream>>>(x, W1, b1, W2, b2, W3, b3, W4, b4,
                                             out, ntiles);
}